// Round 8
// baseline (585.816 us; speedup 1.0000x reference)
//
#include <hip/hip_runtime.h>
#include <stdint.h>

// Problem constants (fixed by reference setup_inputs)
#define TOKENS 4096
#define HIDDEN 4096   // K
#define NQ     4096
#define NKV    1024
#define NTOT   6144   // NQ + 2*NKV
#define KPACK  512    // HIDDEN / 8
#define MAXTILES 20   // max sum_d ceil(cnt_d/256) = 16 + 4

typedef __attribute__((ext_vector_type(8))) __bf16 bf16x8;
typedef __attribute__((ext_vector_type(8))) short short8v;
typedef __attribute__((ext_vector_type(4))) float floatx4;

// fp32 -> bf16 round-to-nearest-even (finite inputs only)
__device__ __forceinline__ short f2bf(float f) {
  union { float f; unsigned u; } v; v.f = f;
  unsigned r = v.u + 0x7fffu + ((v.u >> 16) & 1u);
  return (short)(r >> 16);
}

// async global->LDS, 16B per lane; LDS dest = wave-uniform base + lane*16
__device__ __forceinline__ void load_lds16(const void* g, void* l) {
  __builtin_amdgcn_global_load_lds((__attribute__((address_space(1))) void*)(g),
                                   (__attribute__((address_space(3))) void*)(l),
                                   16, 0, 0);
}

// ---------------------------------------------------------------------------
// Kernel 1: bucket tokens by delta index + build compact tile table.
// grp[0..3]=start, grp[4..7]=count, grp[8]=n_tiles, grp[9..9+nt)=d|(rt<<2).
// Row tiles are 256 tokens (BM=256 in the GEMM).
// ---------------------------------------------------------------------------
__global__ __launch_bounds__(256) void prep_tokens(const int* __restrict__ idx,
                                                   int* __restrict__ token_list,
                                                   int* __restrict__ grp) {
  __shared__ int cnt[4], cur[4];
  const int tid = threadIdx.x;
  if (tid < 4) cnt[tid] = 0;
  __syncthreads();
  for (int t = tid; t < TOKENS; t += 256) {
    int d = idx[t];
    if ((unsigned)d < 4u) atomicAdd(&cnt[d], 1);
  }
  __syncthreads();
  if (tid == 0) {
    int s = 0, nt = 0;
    for (int d = 0; d < 4; d++) {
      cur[d] = s; grp[d] = s; grp[4 + d] = cnt[d]; s += cnt[d];
      int tiles = (cnt[d] + 255) >> 8;
      for (int rt = 0; rt < tiles; rt++) grp[9 + nt++] = d | (rt << 2);
    }
    grp[8] = nt;
  }
  __syncthreads();
  for (int t = tid; t < TOKENS; t += 256) {
    int d = idx[t];
    if ((unsigned)d < 4u) {
      int p = atomicAdd(&cur[d], 1);
      token_list[p] = t;
    }
  }
}

// ---------------------------------------------------------------------------
// Kernel 2: x fp32 -> bf16 (row-major (TOKENS, HIDDEN)); 8 elems/thread.
// ---------------------------------------------------------------------------
__global__ __launch_bounds__(256) void cvt_x(const float* __restrict__ x,
                                             short* __restrict__ xb) {
  size_t g = (size_t)blockIdx.x * 256 + threadIdx.x;
  size_t i = g * 8;
  float4 a = ((const float4*)(x + i))[0];
  float4 b = ((const float4*)(x + i))[1];
  short8v o;
  o[0] = f2bf(a.x); o[1] = f2bf(a.y); o[2] = f2bf(a.z); o[3] = f2bf(a.w);
  o[4] = f2bf(b.x); o[5] = f2bf(b.y); o[6] = f2bf(b.z); o[7] = f2bf(b.w);
  *(short8v*)(xb + i) = o;
}

// ---------------------------------------------------------------------------
// Kernel 3: Wc[d] (NTOT x HIDDEN bf16, B^T layout) = base + dequant(delta_d).
// Round-8 change: base-weight (bw) loads hoisted ABOVE __syncthreads —
// they are LDS-independent, so their HBM latency overlaps the phase-A
// staging drain instead of serializing after the barrier.
// ---------------------------------------------------------------------------
__global__ __launch_bounds__(256) void combine_w(
    const float* __restrict__ bw,
    const int* __restrict__ qwq, const int* __restrict__ qwk, const int* __restrict__ qwv,
    const int* __restrict__ qzq, const int* __restrict__ qzk, const int* __restrict__ qzv,
    const float* __restrict__ scq, const float* __restrict__ sck, const float* __restrict__ scv,
    short* __restrict__ wc) {
  __shared__ int ldsq[4][8][72];
  __shared__ float zs[4][64], ss[4][64];
  const int tid = threadIdx.x;
  const int n0  = blockIdx.y * 64;
  const int kp0 = blockIdx.x * 8;   // k0 = kp0*8

  const int* qw; const int* qz; const float* sc; int Ns, nb;
  if (n0 < NQ)            { qw = qwq; qz = qzq; sc = scq; Ns = NQ;  nb = n0; }
  else if (n0 < NQ + NKV) { qw = qwk; qz = qzk; sc = sck; Ns = NKV; nb = n0 - NQ; }
  else                    { qw = qwv; qz = qzv; sc = scv; Ns = NKV; nb = n0 - NQ - NKV; }

  const int kp = tid & 7;

  // hoisted base-weight loads (independent of LDS; overlap staging latency)
  float4 c00, c01, c10, c11;
  {
    int na = (tid >> 3), nb2 = (tid >> 3) + 32;
    const float4* bp0 = (const float4*)(bw + (size_t)(n0 + na) * HIDDEN + (kp0 + kp) * 8);
    const float4* bp1 = (const float4*)(bw + (size_t)(n0 + nb2) * HIDDEN + (kp0 + kp) * 8);
    c00 = bp0[0]; c01 = bp0[1]; c10 = bp1[0]; c11 = bp1[1];
  }

  // zeros + scales: tid -> (d = tid>>6, n = tid&63)
  {
    int d = tid >> 6, n = tid & 63;
    int nn = nb + n;
    int z = (int)(((unsigned)qz[d * (Ns >> 3) + (nn >> 3)] >> ((nn & 7) * 4)) & 0xFu);
    zs[d][n] = (float)(z + 1);
    ss[d][n] = sc[d * Ns + nn];
  }

  // phase A: stage raw ints (coalesced along n; conflict-free LDS writes)
#pragma unroll
  for (int d = 0; d < 4; d++) {
#pragma unroll
    for (int p = 0; p < 2; p++) {
      int i  = tid + p * 256;
      int kpp = i >> 6, n = i & 63;
      ldsq[d][kpp][n] = qw[((size_t)d * KPACK + kp0 + kpp) * Ns + nb + n];
    }
  }
  __syncthreads();

  // phase B: lane -> (kp = tid&7, n = tid>>3 + p*32); base in regs, d innermost
#pragma unroll
  for (int p = 0; p < 2; p++) {
    int n = (tid >> 3) + p * 32;
    float4 b0 = p ? c10 : c00;
    float4 b1 = p ? c11 : c01;
    float bv[8] = {b0.x, b0.y, b0.z, b0.w, b1.x, b1.y, b1.z, b1.w};
#pragma unroll
    for (int d = 0; d < 4; d++) {
      unsigned q32 = (unsigned)ldsq[d][kp][n];
      float z = zs[d][n], s = ss[d][n];
      short8v o;
#pragma unroll
      for (int j = 0; j < 8; j++)
        o[j] = f2bf(((float)((q32 >> (4 * j)) & 0xFu) - z) * s + bv[j]);
      *(short8v*)(wc + ((size_t)d * NTOT + n0 + n) * HIDDEN + (kp0 + kp) * 8) = o;
    }
  }
}

// ---------------------------------------------------------------------------
// Kernel 4: grouped gathered GEMM. out[tok] = xb[tok] @ Wc[d]^T
//
// v6 = v5 (8-phase m201 port, byte-identical schedule) + bijective XCD
// work swizzle (m204). Evidence: five schedule variants (serial / dbuf /
// ring-4 / reg-dbuf / 8-phase) ALL land 285-326 us at ~35% on every pipe
// -> schedule-invariant limiter. Traffic audit: A re-reads = 24 panels x
// 32MB = 768MB + B 816MB + out 100MB = 1.73GB through L2/L3 per dispatch
// = 5.9 TB/s -> cache-fabric BW candidate. The swizzle gives each XCD a
// contiguous run of ~nwg/8 work-ids (~2 row-tiles), so its A-panels
// (2-4MB) stay in its private 4MB L2: A fabric traffic 768 -> ~270MB.
// If gemm is unchanged (+-3%) the fabric theory is falsified and the
// next move is a traffic-structural rewrite, not more scheduling.
// ---------------------------------------------------------------------------
__device__ __forceinline__ void rdB(const short* Bb, int wn, int mrow, int sx,
                                    bf16x8 bf[4]) {
#pragma unroll
  for (int j = 0; j < 4; j++)
    bf[j] = *(const bf16x8*)(Bb + (wn * 64 + j * 16 + mrow) * 32 + sx);
}
__device__ __forceinline__ void rdA(const short* Ab, int wm, int g, int mrow,
                                    int sx, bf16x8 af[4]) {
#pragma unroll
  for (int i = 0; i < 4; i++)
    af[i] = *(const bf16x8*)(Ab + (wm * 128 + (g * 4 + i) * 16 + mrow) * 32 + sx);
}
__device__ __forceinline__ void mm(const bf16x8 af[4], const bf16x8 bf[4],
                                   floatx4 acc[8][4], int g) {
  __builtin_amdgcn_s_setprio(1);
#pragma unroll
  for (int i = 0; i < 4; i++)
#pragma unroll
    for (int j = 0; j < 4; j++)
      acc[g * 4 + i][j] =
          __builtin_amdgcn_mfma_f32_16x16x32_bf16(af[i], bf[j], acc[g * 4 + i][j], 0, 0, 0);
  __builtin_amdgcn_s_setprio(0);
}
// stage one 16KB half (256 rows x 32 K) of one matrix: 2 loads/thread.
__device__ __forceinline__ void st2(short* dst, const short* g0, const short* g1,
                                    int ko) {
  load_lds16(g0 + ko, dst);
  load_lds16(g1 + ko, dst + 512);
}

#define BARRIER __builtin_amdgcn_s_barrier()
#define LGKM0 asm volatile("s_waitcnt lgkmcnt(0)" ::: "memory")
#define VMC4  asm volatile("s_waitcnt vmcnt(4)" ::: "memory")
#define VMC0  asm volatile("s_waitcnt vmcnt(0)" ::: "memory")

// odd phase: reads kh buffer (B + A m0-3), stages an A-half, computes m0-3
#define PH_O(RB, RA, SD, KO)                                   \
  rdB(RB, wn, mrow, sx, bf);                                   \
  rdA(RA, wm, 0, mrow, sx, af);                                \
  st2((SD) + wave * 1024, gA0, gA1, (KO));                     \
  BARRIER; LGKM0; mm(af, bf, acc, 0); BARRIER;
// even phase: reads A m4-7 (B reused), stages a B-half, vmcnt(4), m4-7
#define PH_E(RA, SD, KO)                                       \
  rdA(RA, wm, 1, mrow, sx, af);                                \
  st2((SD) + wave * 1024, gB0, gB1, (KO));                     \
  VMC4; BARRIER; LGKM0; mm(af, bf, acc, 1); BARRIER;

__global__ __launch_bounds__(512, 2) void gemm_grouped(
    const short* __restrict__ xb, const short* __restrict__ wc,
    const int* __restrict__ token_list, const int* __restrict__ grp,
    float* __restrict__ out) {
  const int nt = grp[8];
  const int nwg = nt * 24;
  const int orig = (int)blockIdx.y * 24 + (int)blockIdx.x;
  if (orig >= nwg) return;
  // m204 bijective XCD swizzle: HW round-robins dispatch order (orig) %8
  // across XCDs; give each XCD a CONTIGUOUS run of work-ids so the ~2
  // row-tiles it owns keep their A-panels resident in its private L2.
  const int q = nwg >> 3, r = nwg & 7, xcd = orig & 7;
  const int w = (xcd < r ? xcd * (q + 1) : r * (q + 1) + (xcd - r) * q) + (orig >> 3);
  const int te = grp[9 + w / 24];
  const int d  = te & 3;
  const int rt = te >> 2;
  const int cnt   = grp[4 + d];
  const int start = grp[d];
  const int n0 = (w % 24) * 256;

  // [dbuf][kh][256 rows x 32 K] 16KB halves; total 128 KB
  __shared__ __align__(16) short Ak[2][2][8192];
  __shared__ __align__(16) short Bk[2][2][8192];
  __shared__ int toks[256];

  const int tid = threadIdx.x;
  if (tid < 256) {
    int rr = rt * 256 + tid;
    if (rr >= cnt) rr = cnt - 1;        // clamp tail (stores guarded below)
    toks[tid] = token_list[start + rr];
  }
  __syncthreads();

  const int wave = tid >> 6;
  const int lane = tid & 63;

  // stage source pre-swizzle: unit u holds seg (u&3)^((u>>3)&3); per wave
  // instr covers units w*128 + j*64 + lane -> seg = (lane&3)^((lane>>3)&3)
  const int sw = ((lane & 3) ^ ((lane >> 3) & 3)) * 8;  // shorts

  // per-lane row pointers: instr j of wave w covers rows w*32 + j*16 + (lane>>2)
  const int arow = wave * 32 + (lane >> 2);
  const short* gA0 = xb + (size_t)toks[arow] * HIDDEN + sw;
  const short* gA1 = xb + (size_t)toks[arow + 16] * HIDDEN + sw;
  const short* wrow = wc + ((size_t)d * NTOT + n0) * HIDDEN;
  const short* gB0 = wrow + (size_t)arow * HIDDEN + sw;
  const short* gB1 = gB0 + (size_t)16 * HIDDEN;

  const int mrow = lane & 15;
  // fragment read: (row r, kseg s) at unit r*4 + (s ^ ((r>>1)&3));
  // row bases are multiples of 16 -> (r>>1)&3 == (mrow>>1)&3
  const int sx = (((lane >> 4) ^ ((mrow >> 1) & 3))) * 8;
  const int wm = wave >> 2;   // 0..1  (M half)
  const int wn = wave & 3;    // 0..3  (N quarter)

  floatx4 acc[8][4];
#pragma unroll
  for (int i = 0; i < 8; i++)
#pragma unroll
    for (int j = 0; j < 4; j++) acc[i][j] = (floatx4){0.f, 0.f, 0.f, 0.f};

  bf16x8 af[4], bf[4];

  // prologue: stage tile 0 (kh0 A,B then kh1 A,B = 8 loads); vmcnt(4)
  // leaves kh1 (4 loads) in flight == steady-state iter-entry invariant.
  st2(&Ak[0][0][0] + wave * 1024, gA0, gA1, 0);
  st2(&Bk[0][0][0] + wave * 1024, gB0, gB1, 0);
  st2(&Ak[0][1][0] + wave * 1024, gA0, gA1, 32);
  st2(&Bk[0][1][0] + wave * 1024, gB0, gB1, 32);
  VMC4;
  BARRIER;

  // main loop: iter it covers tiles 2it (buf0), 2it+1 (buf1);
  // stages tile 2it+1 (ph1-4) and 2it+2 (ph5-8). Tiles 0..61 here.
  for (int it = 0; it < 31; ++it) {
    const int kb = it * 128;
    PH_O(&Bk[0][0][0], &Ak[0][0][0], &Ak[1][0][0], kb + 64);
    PH_E(&Ak[0][0][0],               &Bk[1][0][0], kb + 64);
    PH_O(&Bk[0][1][0], &Ak[0][1][0], &Ak[1][1][0], kb + 96);
    PH_E(&Ak[0][1][0],               &Bk[1][1][0], kb + 96);
    PH_O(&Bk[1][0][0], &Ak[1][0][0], &Ak[0][0][0], kb + 128);
    PH_E(&Ak[1][0][0],               &Bk[0][0][0], kb + 128);
    PH_O(&Bk[1][1][0], &Ak[1][1][0], &Ak[0][1][0], kb + 160);
    PH_E(&Ak[1][1][0],               &Bk[0][1][0], kb + 160);
  }
  // peeled last iteration: tiles 62 (buf0), 63 (buf1); stage tile 63 only.
  PH_O(&Bk[0][0][0], &Ak[0][0][0], &Ak[1][0][0], 4032);
  PH_E(&Ak[0][0][0],               &Bk[1][0][0], 4032);
  PH_O(&Bk[0][1][0], &Ak[0][1][0], &Ak[1][1][0], 4064);
  PH_E(&Ak[0][1][0],               &Bk[1][1][0], 4064);
  // ph5-8: no stages; vmcnt(0) once (tile 63 kh1) before its reads.
  rdB(&Bk[1][0][0], wn, mrow, sx, bf);
  rdA(&Ak[1][0][0], wm, 0, mrow, sx, af);
  BARRIER; LGKM0; mm(af, bf, acc, 0); BARRIER;
  rdA(&Ak[1][0][0], wm, 1, mrow, sx, af);
  VMC0; BARRIER; LGKM0; mm(af, bf, acc, 1); BARRIER;
  rdB(&Bk[1][1][0], wn, mrow, sx, bf);
  rdA(&Ak[1][1][0], wm, 0, mrow, sx, af);
  BARRIER; LGKM0; mm(af, bf, acc, 0); BARRIER;
  rdA(&Ak[1][1][0], wm, 1, mrow, sx, af);
  BARRIER; LGKM0; mm(af, bf, acc, 1);

  // epilogue: C/D layout col = lane&15, row = (lane>>4)*4 + reg
  const int rbase = (lane >> 4) * 4;
  const int coll  = lane & 15;
#pragma unroll
  for (int i = 0; i < 8; i++) {
#pragma unroll
    for (int rr = 0; rr < 4; rr++) {
      int m = wm * 128 + i * 16 + rbase + rr;
      if (rt * 256 + m < cnt) {
        float* orow = out + (size_t)toks[m] * NTOT + n0 + wn * 64 + coll;
#pragma unroll
        for (int j = 0; j < 4; j++) orow[j * 16] = acc[i][j][rr];
      }
    }
  }
}

// ---------------------------------------------------------------------------
extern "C" void kernel_launch(void* const* d_in, const int* in_sizes, int n_in,
                              void* d_out, int out_size, void* d_ws, size_t ws_size,
                              hipStream_t stream) {
  const float* x   = (const float*)d_in[0];
  const float* bw  = (const float*)d_in[1];
  const int*   qwq = (const int*)d_in[2];
  const int*   qwk = (const int*)d_in[3];
  const int*   qwv = (const int*)d_in[4];
  const int*   qzq = (const int*)d_in[5];
  const int*   qzk = (const int*)d_in[6];
  const int*   qzv = (const int*)d_in[7];
  const float* scq = (const float*)d_in[8];
  const float* sck = (const float*)d_in[9];
  const float* scv = (const float*)d_in[10];
  const int*   idx = (const int*)d_in[11];
  float* out = (float*)d_out;

  // workspace layout (needs ~235 MB)
  char* ws = (char*)d_ws;
  short* xb = (short*)ws;                                       // 33,554,432 B
  short* wc = (short*)(ws + (size_t)33554432);                  // 201,326,592 B
  int* token_list = (int*)(ws + (size_t)33554432 + 201326592);  // 16,384 B
  int* grp = token_list + TOKENS;                               // 256 B

  prep_tokens<<<1, 256, 0, stream>>>(idx, token_list, grp);
  cvt_x<<<(TOKENS * HIDDEN) / (256 * 8), 256, 0, stream>>>(x, xb);
  dim3 gc(HIDDEN / 64, NTOT / 64);  // (64, 96)
  combine_w<<<gc, 256, 0, stream>>>(bw, qwq, qwk, qwv, qzq, qzk, qzv, scq, sck, scv, wc);
  dim3 gg(NTOT / 256, MAXTILES);  // (24, 20)
  gemm_grouped<<<gg, 512, 0, stream>>>(xb, wc, token_list, grp, out);
}